// Round 10
// baseline (71.523 us; speedup 1.0000x reference)
//
#include <hip/hip_runtime.h>

typedef _Float16 f16;
typedef _Float16 f16x4 __attribute__((ext_vector_type(4)));
typedef _Float16 f16x8 __attribute__((ext_vector_type(8)));
typedef float f32x4 __attribute__((ext_vector_type(4)));

typedef __attribute__((address_space(1))) void gvoid;
typedef __attribute__((address_space(3))) void lvoid;
#define GLD16(gp, lp) __builtin_amdgcn_global_load_lds((gvoid*)(gp), (lvoid*)(lp), 16, 0, 0)

__device__ __forceinline__ f32x4 mfma16(f16x8 a, f16x8 b, f32x4 c) {
    return __builtin_amdgcn_mfma_f32_16x16x32_f16(a, b, c, 0, 0, 0);
}
__device__ __forceinline__ f32x4 mfma16k16(f16x4 a, f16x4 b, f32x4 c) {
    return __builtin_amdgcn_mfma_f32_16x16x16f16(a, b, c, 0, 0, 0);
}

// ---- prep: LN (blocks 0..2047) + wqkv transpose (2048..2239) + wout transpose (2240..2303)
__global__ __launch_bounds__(256) void k_prep(
    const float* __restrict__ x, const float* __restrict__ gamma,
    const float* __restrict__ beta, const int* __restrict__ mlab,
    const float* __restrict__ wqkv, const float* __restrict__ wout,
    f16* __restrict__ h, f16* __restrict__ wqkvT, f16* __restrict__ woutT)
{
    __shared__ float t[64][65];
    int bid = blockIdx.x, tid = threadIdx.x;
    if (bid < 2048) {                       // ---- LayerNorm, 1 wave/row ----
        int row = bid * 4 + (tid >> 6);
        int b = row >> 10, seg = (row >> 8) & 3;
        if (mlab[b * 4 + seg] == 0) return;
        int lane = tid & 63;
        const float* xr = x + (size_t)row * 512;
        float4 a = ((const float4*)xr)[lane * 2];
        float4 bv = ((const float4*)xr)[lane * 2 + 1];
        float v[8] = {a.x, a.y, a.z, a.w, bv.x, bv.y, bv.z, bv.w};
        float s = 0.f, s2 = 0.f;
#pragma unroll
        for (int j = 0; j < 8; ++j) { s += v[j]; s2 += v[j] * v[j]; }
#pragma unroll
        for (int off = 1; off < 64; off <<= 1) {
            s  += __shfl_xor(s, off);
            s2 += __shfl_xor(s2, off);
        }
        float mu  = s * (1.f / 512.f);
        float var = s2 * (1.f / 512.f) - mu * mu;
        float rstd = rsqrtf(var + 1e-5f);
        float4 g0 = ((const float4*)gamma)[lane * 2];
        float4 g1 = ((const float4*)gamma)[lane * 2 + 1];
        float4 b0 = ((const float4*)beta)[lane * 2];
        float4 b1 = ((const float4*)beta)[lane * 2 + 1];
        float g[8]  = {g0.x, g0.y, g0.z, g0.w, g1.x, g1.y, g1.z, g1.w};
        float bb[8] = {b0.x, b0.y, b0.z, b0.w, b1.x, b1.y, b1.z, b1.w};
        f16x8 o;
#pragma unroll
        for (int j = 0; j < 8; ++j) o[j] = (f16)((v[j] - mu) * rstd * g[j] + bb[j]);
        *(f16x8*)&h[(size_t)row * 512 + lane * 8] = o;
        return;
    }
    const float* in; f16* out; int C, c0, r0;
    if (bid < 2240) { int idx = bid - 2048; in = wqkv; out = wqkvT; C = 1536; c0 = (idx % 24) * 64; r0 = (idx / 24) * 64; }
    else            { int idx = bid - 2240; in = wout; out = woutT; C = 512;  c0 = (idx % 8)  * 64; r0 = (idx / 8)  * 64; }
#pragma unroll
    for (int i = 0; i < 16; ++i) {
        int r = i * 4 + (tid >> 6), c = tid & 63;
        t[r][c] = in[(size_t)(r0 + r) * C + c0 + c];
    }
    __syncthreads();
#pragma unroll
    for (int i = 0; i < 16; ++i) {
        int cr = i * 4 + (tid >> 6), cc = tid & 63;
        out[(size_t)(c0 + cr) * 512 + r0 + cc] = (f16)t[cc][cr];
    }
}

// ---- QKV GEMM: 64x128 tile, BK=64, LDS dbuf, swizzled; LDS-repacked 16B epilogue ----
__global__ __launch_bounds__(256, 3) void k_gemm_qkv(
    const f16* __restrict__ A, const f16* __restrict__ Bt, const int* __restrict__ mlab,
    f16* __restrict__ q, f16* __restrict__ kmat, f16* __restrict__ vt)
{
    __shared__ __align__(16) f16 SM[24576];
    int tid = threadIdx.x, wid = tid >> 6, lane = tid & 63;
    int wm = wid >> 1, wn = wid & 1;
    int l15 = lane & 15, l4 = lane >> 4;
    int rowBase = blockIdx.y * 64;
    int colBase = blockIdx.x * 128;
    if (mlab[(rowBase >> 10) * 4 + ((rowBase & 1023) >> 8)] == 0) return;

    int srow = lane >> 3;
    int scolz = ((lane & 7) ^ srow) << 3;
    int kxor = (l15 & 7) << 3;

#define STG(bi, kt)                                                                              \
    do {                                                                                         \
        _Pragma("unroll") for (int i_ = 0; i_ < 2; ++i_) {                                       \
            int rg = (wid * 2 + i_) * 8;                                                         \
            GLD16(&A[(size_t)(rowBase + rg + srow) * 512 + (kt) + scolz], SM + (bi)*4096 + rg*64);\
        }                                                                                        \
        _Pragma("unroll") for (int i_ = 0; i_ < 4; ++i_) {                                       \
            int rg = (wid * 4 + i_) * 8;                                                         \
            GLD16(&Bt[(size_t)(colBase + rg + srow) * 512 + (kt) + scolz], SM + 8192 + (bi)*8192 + rg*64);\
        }                                                                                        \
    } while (0)

    f32x4 acc[2][4] = {};
    STG(0, 0);
    for (int ki = 0; ki < 8; ++ki) {
        int bi = ki & 1;
        __syncthreads();
        if (ki < 7) STG(bi ^ 1, (ki + 1) * 64);
#pragma unroll
        for (int kk = 0; kk < 2; ++kk) {
            f16x8 af[2], bf[4];
#pragma unroll
            for (int m = 0; m < 2; ++m)
                af[m] = *(const f16x8*)&SM[bi*4096 + (wm * 32 + m * 16 + l15) * 64 + ((kk * 32 + l4 * 8) ^ kxor)];
#pragma unroll
            for (int n = 0; n < 4; ++n)
                bf[n] = *(const f16x8*)&SM[8192 + bi*8192 + (wn * 64 + n * 16 + l15) * 64 + ((kk * 32 + l4 * 8) ^ kxor)];
#pragma unroll
            for (int m = 0; m < 2; ++m)
#pragma unroll
                for (int n = 0; n < 4; ++n)
                    acc[m][n] = mfma16(af[m], bf[n], acc[m][n]);
        }
    }
#undef STG

    __syncthreads();
    bool isV = (colBase >= 1024);
    if (!isV) {
#pragma unroll
        for (int m = 0; m < 2; ++m)
#pragma unroll
            for (int n = 0; n < 4; ++n)
#pragma unroll
                for (int r = 0; r < 4; ++r)
                    SM[(wm*32 + m*16 + l4*4 + r) * 136 + wn*64 + n*16 + l15] = (f16)acc[m][n][r];
        __syncthreads();
        int rl = tid >> 2, cl0 = (tid & 3) * 32;
        int row = rowBase + rl, bq = row >> 10, nt = row & 1023;
#pragma unroll
        for (int jj = 0; jj < 4; ++jj) {
            f16x8 v = *(const f16x8*)&SM[rl * 136 + cl0 + jj * 8];
            int col = colBase + cl0 + jj * 8;
            int which = col >> 9, hh2 = (col >> 6) & 7, d = col & 63;
            f16* dst = which ? kmat : q;
            *(f16x8*)&dst[((size_t)(bq * 8 + hh2) * 1024 + nt) * 64 + d] = v;
        }
    } else {
#pragma unroll
        for (int m = 0; m < 2; ++m)
#pragma unroll
            for (int n = 0; n < 4; ++n)
#pragma unroll
                for (int r = 0; r < 4; ++r)
                    SM[(wn*64 + n*16 + l15) * 72 + wm*32 + m*16 + l4*4 + r] = (f16)acc[m][n][r];
        __syncthreads();
        int cl = tid >> 1, rl0 = (tid & 1) * 32;
        int col = colBase + cl, hh2 = (col >> 6) & 7, d = col & 63;
        int bq = rowBase >> 10, ntb = (rowBase & 1023) + rl0;
        f16* dstrow = vt + ((size_t)(bq * 8 + hh2) * 64 + d) * 1024 + ntb;
#pragma unroll
        for (int jj = 0; jj < 4; ++jj)
            *(f16x8*)&dstrow[jj * 8] = *(const f16x8*)&SM[cl * 72 + rl0 + jj * 8];
    }
}

// ---- masked flash attention v10: 16-token chunks, K=16 PV (zero-shuffle P), 3 blocks/CU ----
// 1024 blocks x 512 threads; 4 chunk-groups x 2 q-slices; dbuf GLD16; 1 barrier/iter.
__global__ __launch_bounds__(512, 6) void k_attn(
    const f16* __restrict__ q, const f16* __restrict__ kmat,
    const f16* __restrict__ vt, const int* __restrict__ mlab,
    f16* __restrict__ ao)
{
    __shared__ __align__(16) f16 KV[16384];   // K: (g*2+bi)*1024; V: 8192+(g*2+bi)*1024; merge aliases f16[4][64][64]
    __shared__ float ML[512];                 // m: [g*64+q]; l: [256+g*64+q]

    int bid = blockIdx.x;
    int bh = (bid & 7) + 8 * (bid >> 7);      // all 16 q-blocks of a bh on one XCD
    int qb = (bid >> 3) & 15;
    int b = bh >> 3, hh = bh & 7;
    int tid = threadIdx.x, wid = tid >> 6, lane = tid & 63;
    int g = wid >> 1, qs = wid & 1;
    int l15 = lane & 15, l4 = lane >> 4;
    int qbase = qb * 64;
    size_t bhs = (size_t)bh;

    if (mlab[b * 4 + (qb >> 2)] == 0) return;  // rows filled by k_gemm_out bias path

    unsigned ps = 0; int npres = 0;
#pragma unroll
    for (int s = 0; s < 4; ++s)
        if (mlab[b * 4 + s] != 0) { ps |= (unsigned)s << (4 * npres); ++npres; }
    int niter = npres * 4;                    // 16-token chunks, 4 groups
#define T0C(c) ((int)((ps >> (4 * ((c) >> 4))) & 15) * 256 + ((c) & 15) * 16)

    // Q fragments: rows qs*32 + {0,16} + l15, pre-scaled by 1/8
    f16x8 qf0[2], qf1[2];
#pragma unroll
    for (int kk = 0; kk < 2; ++kk) {
        qf0[kk] = *(const f16x8*)&q[(bhs * 1024 + qbase + qs * 32 + l15) * 64 + kk * 32 + l4 * 8];
        qf1[kk] = *(const f16x8*)&q[(bhs * 1024 + qbase + qs * 32 + 16 + l15) * 64 + kk * 32 + l4 * 8];
#pragma unroll
        for (int j = 0; j < 8; ++j) { qf0[kk][j] = qf0[kk][j] * (f16)0.125; qf1[kk][j] = qf1[kk][j] * (f16)0.125; }
    }

    // staging: group = 2 waves; slot s = qs*64+lane (128 slots of 16B per K or V tile)
    int s0 = qs * 64 + lane;
    int krow = s0 >> 3, kpos = (s0 & 7) ^ (krow & 7);
    int vrow = s0 >> 1, vhalf = (s0 & 1) ^ ((s0 >> 3) & 1);
    const f16* kg = kmat + (bhs * 1024 + krow) * 64 + kpos * 8;  // + t0*64
    const f16* vg = vt + (bhs * 64 + vrow) * 1024 + vhalf * 8;   // + t0

#define STAGE(bi, t0)                                            \
    do {                                                         \
        GLD16(kg + (size_t)(t0) * 64, KV + (g * 2 + (bi)) * 1024 + qs * 512);        \
        GLD16(vg + (t0), KV + 8192 + (g * 2 + (bi)) * 1024 + qs * 512);              \
    } while (0)

    float mrun0 = -1e30f, mrun1 = -1e30f, lrun0 = 0.f, lrun1 = 0.f;
    f32x4 o0[4] = {}, o1[4] = {};
    int kx = l15 & 7;

    STAGE(0, T0C(g));

    for (int i = 0; i < niter; ++i) {
        int bi = i & 1;
        __syncthreads();                      // buf bi ready; bi^1 free
        if (i + 1 < niter) STAGE(bi ^ 1, T0C(4 * (i + 1) + g));

        const f16* Kt = KV + (g * 2 + bi) * 1024;
        const f16* Vt = KV + 8192 + (g * 2 + bi) * 1024;

        // QK^T: S^T[tok l4*4+r][q l15], K fragment shared by both q-frags
        f32x4 s00 = {}, s10 = {};
        __builtin_amdgcn_s_setprio(1);
#pragma unroll
        for (int kk = 0; kk < 2; ++kk) {
            f16x8 ka = *(const f16x8*)&Kt[l15 * 64 + (((kk * 4 + l4) ^ kx) << 3)];
            s00 = mfma16(ka, qf0[kk], s00);
            s10 = mfma16(ka, qf1[kk], s10);
        }
        __builtin_amdgcn_s_setprio(0);

        // lane-local online softmax; P lands directly in PV B-operand layout (k = l4*4+j)
        f16x4 pb0, pb1;
        {
            float mx = fmaxf(fmaxf(s00[0], s00[1]), fmaxf(s00[2], s00[3]));
            mx = fmaxf(mx, __shfl_xor(mx, 16));
            mx = fmaxf(mx, __shfl_xor(mx, 32));
            float mnew = fmaxf(mrun0, mx);
            float alpha = __expf(mrun0 - mnew);
            mrun0 = mnew;
            float rs = 0.f;
#pragma unroll
            for (int r = 0; r < 4; ++r) {
                float p = __expf(s00[r] - mnew);
                rs += p;
                pb0[r] = (f16)p;
            }
            rs += __shfl_xor(rs, 16);
            rs += __shfl_xor(rs, 32);
            lrun0 = lrun0 * alpha + rs;
#pragma unroll
            for (int nd = 0; nd < 4; ++nd) o0[nd] *= alpha;
        }
        {
            float mx = fmaxf(fmaxf(s10[0], s10[1]), fmaxf(s10[2], s10[3]));
            mx = fmaxf(mx, __shfl_xor(mx, 16));
            mx = fmaxf(mx, __shfl_xor(mx, 32));
            float mnew = fmaxf(mrun1, mx);
            float alpha = __expf(mrun1 - mnew);
            mrun1 = mnew;
            float rs = 0.f;
#pragma unroll
            for (int r = 0; r < 4; ++r) {
                float p = __expf(s10[r] - mnew);
                rs += p;
                pb1[r] = (f16)p;
            }
            rs += __shfl_xor(rs, 16);
            rs += __shfl_xor(rs, 32);
            lrun1 = lrun1 * alpha + rs;
#pragma unroll
            for (int nd = 0; nd < 4; ++nd) o1[nd] *= alpha;
        }

        // PV via K=16 MFMA: va = V^T[d row][tok l4*4+j] (8B reads, slot-xor swizzled)
        __builtin_amdgcn_s_setprio(1);
#pragma unroll
        for (int nd = 0; nd < 4; ++nd) {
            int row = nd * 16 + l15;
            int sub = (((l4 >> 1) ^ ((row >> 2) & 1)) << 1) | (l4 & 1);
            f16x4 va = *(const f16x4*)&Vt[row * 16 + sub * 4];
            o0[nd] = mfma16k16(va, pb0, o0[nd]);
            o1[nd] = mfma16k16(va, pb1, o1[nd]);
        }
        __builtin_amdgcn_s_setprio(0);
    }
#undef STAGE
#undef T0C

    // ---- publish partials as f16 (all groups) ----
    __syncthreads();                          // staging dead; alias KV
    f16* mg = KV;                             // [g][q 64][d 64] f16 = 32KB
    int q0 = qs * 32 + l15, q1 = q0 + 16;
    if (l4 == 0) {
        ML[g * 64 + q0] = mrun0;       ML[256 + g * 64 + q0] = lrun0;
        ML[g * 64 + q1] = mrun1;       ML[256 + g * 64 + q1] = lrun1;
    }
#pragma unroll
    for (int nd = 0; nd < 4; ++nd) {
        f16x4 w0, w1;
#pragma unroll
        for (int r = 0; r < 4; ++r) { w0[r] = (f16)o0[nd][r]; w1[r] = (f16)o1[nd][r]; }
        *(f16x4*)&mg[g * 4096 + q0 * 64 + (((nd * 4 + l4) ^ (q0 & 7)) << 2)] = w0;
        *(f16x4*)&mg[g * 4096 + q1 * 64 + (((nd * 4 + l4) ^ (q1 & 7)) << 2)] = w1;
    }
    __syncthreads();

    // ---- distributed 4-way merge; 16B coalesced ao stores ----
    {
        int qq = l15 + l4 * 16;               // 0..63
        float m0 = ML[qq], m1 = ML[64 + qq], m2 = ML[128 + qq], m3 = ML[192 + qq];
        float M = fmaxf(fmaxf(m0, m1), fmaxf(m2, m3));
        float e0 = __expf(m0 - M), e1 = __expf(m1 - M), e2 = __expf(m2 - M), e3 = __expf(m3 - M);
        float L = ML[256 + qq] * e0 + ML[320 + qq] * e1 + ML[384 + qq] * e2 + ML[448 + qq] * e3;
        float inv = 1.f / L;
        int posA = ((wid * 2) ^ (qq & 7)) << 2;
        int posB = ((wid * 2 + 1) ^ (qq & 7)) << 2;
        f32x4 accA = {}, accB = {};
#pragma unroll
        for (int gg = 0; gg < 4; ++gg) {
            float eg = gg == 0 ? e0 : gg == 1 ? e1 : gg == 2 ? e2 : e3;
            f16x4 pa = *(const f16x4*)&mg[gg * 4096 + qq * 64 + posA];
            f16x4 pc = *(const f16x4*)&mg[gg * 4096 + qq * 64 + posB];
#pragma unroll
            for (int r = 0; r < 4; ++r) { accA[r] += eg * (float)pa[r]; accB[r] += eg * (float)pc[r]; }
        }
        union { f16 h[8]; f16x8 v; } w;
#pragma unroll
        for (int r = 0; r < 4; ++r) {
            w.h[r] = (f16)(accA[r] * inv);
            w.h[4 + r] = (f16)(accB[r] * inv);
        }
        *(f16x8*)&ao[(size_t)(b * 1024 + qbase + qq) * 512 + hh * 64 + wid * 8] = w.v;
    }
}

// ---- out GEMM: 64x128 tile, LDS dbuf, single barrier/K-step, swizzled ----
__global__ __launch_bounds__(256, 3) void k_gemm_out(
    const f16* __restrict__ A, const f16* __restrict__ Bt, const int* __restrict__ mlab,
    const float* __restrict__ bias, float* __restrict__ out)
{
    __shared__ f16 As[2][64 * 64];
    __shared__ f16 Bs[2][128 * 64];
    int tid = threadIdx.x, wid = tid >> 6, lane = tid & 63;
    int wm = wid >> 1, wn = wid & 1;
    int l15 = lane & 15, l4 = lane >> 4;
    int rowBase = blockIdx.y * 64;
    int colBase = blockIdx.x * 128;
    if (mlab[(rowBase >> 10) * 4 + ((rowBase & 1023) >> 8)] == 0) {
        for (int i = tid; i < 64 * 128; i += 256)
            out[(size_t)(rowBase + (i >> 7)) * 512 + colBase + (i & 127)] = bias[colBase + (i & 127)];
        return;
    }

    int srow = lane >> 3;
    int scolz = ((lane & 7) ^ srow) << 3;
    int kxor = (l15 & 7) << 3;

#define STG(bi, kt)                                                                         \
    do {                                                                                    \
        _Pragma("unroll") for (int i_ = 0; i_ < 2; ++i_) {                                  \
            int rg = (wid * 2 + i_) * 8;                                                    \
            GLD16(&A[(size_t)(rowBase + rg + srow) * 512 + (kt) + scolz], &As[bi][rg * 64]);\
        }                                                                                   \
        _Pragma("unroll") for (int i_ = 0; i_ < 4; ++i_) {                                  \
            int rg = (wid * 4 + i_) * 8;                                                    \
            GLD16(&Bt[(size_t)(colBase + rg + srow) * 512 + (kt) + scolz], &Bs[bi][rg * 64]);\
        }                                                                                   \
    } while (0)

    f32x4 acc[2][4] = {};
    STG(0, 0);
    for (int ki = 0; ki < 8; ++ki) {
        int bi = ki & 1;
        __syncthreads();
        if (ki < 7) STG(bi ^ 1, (ki + 1) * 64);
#pragma unroll
        for (int kk = 0; kk < 2; ++kk) {
            f16x8 af[2], bf[4];
#pragma unroll
            for (int m = 0; m < 2; ++m)
                af[m] = *(const f16x8*)&As[bi][(wm * 32 + m * 16 + l15) * 64 + ((kk * 32 + l4 * 8) ^ kxor)];
#pragma unroll
            for (int n = 0; n < 4; ++n)
                bf[n] = *(const f16x8*)&Bs[bi][(wn * 64 + n * 16 + l15) * 64 + ((kk * 32 + l4 * 8) ^ kxor)];
#pragma unroll
            for (int m = 0; m < 2; ++m)
#pragma unroll
                for (int n = 0; n < 4; ++n)
                    acc[m][n] = mfma16(af[m], bf[n], acc[m][n]);
        }
    }
#undef STG
#pragma unroll
    for (int m = 0; m < 2; ++m)
#pragma unroll
        for (int n = 0; n < 4; ++n)
#pragma unroll
            for (int r = 0; r < 4; ++r) {
                int row = rowBase + wm * 32 + m * 16 + l4 * 4 + r;
                int col = colBase + wn * 64 + n * 16 + l15;
                out[(size_t)row * 512 + col] = acc[m][n][r] + bias[col];
            }
}

extern "C" void kernel_launch(void* const* d_in, const int* in_sizes, int n_in,
                              void* d_out, int out_size, void* d_ws, size_t ws_size,
                              hipStream_t stream) {
    const float* x     = (const float*)d_in[0];
    const int*   mlab  = (const int*)d_in[1];
    const float* gamma = (const float*)d_in[2];
    const float* beta  = (const float*)d_in[3];
    const float* wqkv  = (const float*)d_in[4];
    const float* wout  = (const float*)d_in[5];
    const float* bout  = (const float*)d_in[6];
    float* out = (float*)d_out;

    f16* h     = (f16*)d_ws;                 // 8192*512
    f16* wqkvT = h + 8192 * 512;             // 1536*512
    f16* woutT = wqkvT + 1536 * 512;         // 512*512
    f16* q     = woutT + 512 * 512;          // [B*H][1024][64]
    f16* kmat  = q + 4 * 1024 * 1024;
    f16* vt    = kmat + 4 * 1024 * 1024;     // [B*H][64][1024]
    f16* ao    = h;                          // h dead after QKV GEMM -> reuse

    k_prep<<<2304, 256, 0, stream>>>(x, gamma, beta, mlab, wqkv, wout, h, wqkvT, woutT);
    k_gemm_qkv<<<dim3(12, 128), 256, 0, stream>>>(h, wqkvT, mlab, q, kmat, vt);
    k_attn<<<1024, 512, 0, stream>>>(q, kmat, vt, mlab, ao);
    k_gemm_out<<<dim3(4, 128), 256, 0, stream>>>(ao, woutT, mlab, bout, out);
}

// Round 11
// 61.013 us; speedup vs baseline: 1.1723x; 1.1723x over previous
//
#include <hip/hip_runtime.h>

typedef _Float16 f16;
typedef _Float16 f16x4 __attribute__((ext_vector_type(4)));
typedef _Float16 f16x8 __attribute__((ext_vector_type(8)));
typedef float f32x4 __attribute__((ext_vector_type(4)));

typedef __attribute__((address_space(1))) void gvoid;
typedef __attribute__((address_space(3))) void lvoid;
#define GLD16(gp, lp) __builtin_amdgcn_global_load_lds((gvoid*)(gp), (lvoid*)(lp), 16, 0, 0)

__device__ __forceinline__ f32x4 mfma16(f16x8 a, f16x8 b, f32x4 c) {
    return __builtin_amdgcn_mfma_f32_16x16x32_f16(a, b, c, 0, 0, 0);
}
__device__ __forceinline__ f32x4 mfma16k16(f16x4 a, f16x4 b, f32x4 c) {
    return __builtin_amdgcn_mfma_f32_16x16x16f16(a, b, c, 0, 0, 0);
}

// ---- prep: LN (blocks 0..2047) + wqkv transpose (2048..2239) + wout transpose (2240..2303)
__global__ __launch_bounds__(256) void k_prep(
    const float* __restrict__ x, const float* __restrict__ gamma,
    const float* __restrict__ beta, const int* __restrict__ mlab,
    const float* __restrict__ wqkv, const float* __restrict__ wout,
    f16* __restrict__ h, f16* __restrict__ wqkvT, f16* __restrict__ woutT)
{
    __shared__ float t[64][65];
    int bid = blockIdx.x, tid = threadIdx.x;
    if (bid < 2048) {                       // ---- LayerNorm, 1 wave/row ----
        int row = bid * 4 + (tid >> 6);
        int b = row >> 10, seg = (row >> 8) & 3;
        if (mlab[b * 4 + seg] == 0) return;
        int lane = tid & 63;
        const float* xr = x + (size_t)row * 512;
        float4 a = ((const float4*)xr)[lane * 2];
        float4 bv = ((const float4*)xr)[lane * 2 + 1];
        float v[8] = {a.x, a.y, a.z, a.w, bv.x, bv.y, bv.z, bv.w};
        float s = 0.f, s2 = 0.f;
#pragma unroll
        for (int j = 0; j < 8; ++j) { s += v[j]; s2 += v[j] * v[j]; }
#pragma unroll
        for (int off = 1; off < 64; off <<= 1) {
            s  += __shfl_xor(s, off);
            s2 += __shfl_xor(s2, off);
        }
        float mu  = s * (1.f / 512.f);
        float var = s2 * (1.f / 512.f) - mu * mu;
        float rstd = rsqrtf(var + 1e-5f);
        float4 g0 = ((const float4*)gamma)[lane * 2];
        float4 g1 = ((const float4*)gamma)[lane * 2 + 1];
        float4 b0 = ((const float4*)beta)[lane * 2];
        float4 b1 = ((const float4*)beta)[lane * 2 + 1];
        float g[8]  = {g0.x, g0.y, g0.z, g0.w, g1.x, g1.y, g1.z, g1.w};
        float bb[8] = {b0.x, b0.y, b0.z, b0.w, b1.x, b1.y, b1.z, b1.w};
        f16x8 o;
#pragma unroll
        for (int j = 0; j < 8; ++j) o[j] = (f16)((v[j] - mu) * rstd * g[j] + bb[j]);
        *(f16x8*)&h[(size_t)row * 512 + lane * 8] = o;
        return;
    }
    const float* in; f16* out; int C, c0, r0;
    if (bid < 2240) { int idx = bid - 2048; in = wqkv; out = wqkvT; C = 1536; c0 = (idx % 24) * 64; r0 = (idx / 24) * 64; }
    else            { int idx = bid - 2240; in = wout; out = woutT; C = 512;  c0 = (idx % 8)  * 64; r0 = (idx / 8)  * 64; }
#pragma unroll
    for (int i = 0; i < 16; ++i) {
        int r = i * 4 + (tid >> 6), c = tid & 63;
        t[r][c] = in[(size_t)(r0 + r) * C + c0 + c];
    }
    __syncthreads();
#pragma unroll
    for (int i = 0; i < 16; ++i) {
        int cr = i * 4 + (tid >> 6), cc = tid & 63;
        out[(size_t)(c0 + cr) * 512 + r0 + cc] = (f16)t[cc][cr];
    }
}

// ---- QKV GEMM: 64x128 tile, BK=64, LDS dbuf, swizzled; LDS-repacked 16B epilogue ----
__global__ __launch_bounds__(256, 3) void k_gemm_qkv(
    const f16* __restrict__ A, const f16* __restrict__ Bt, const int* __restrict__ mlab,
    f16* __restrict__ q, f16* __restrict__ kmat, f16* __restrict__ vt)
{
    __shared__ __align__(16) f16 SM[24576];
    int tid = threadIdx.x, wid = tid >> 6, lane = tid & 63;
    int wm = wid >> 1, wn = wid & 1;
    int l15 = lane & 15, l4 = lane >> 4;
    int rowBase = blockIdx.y * 64;
    int colBase = blockIdx.x * 128;
    if (mlab[(rowBase >> 10) * 4 + ((rowBase & 1023) >> 8)] == 0) return;

    int srow = lane >> 3;
    int scolz = ((lane & 7) ^ srow) << 3;
    int kxor = (l15 & 7) << 3;

#define STG(bi, kt)                                                                              \
    do {                                                                                         \
        _Pragma("unroll") for (int i_ = 0; i_ < 2; ++i_) {                                       \
            int rg = (wid * 2 + i_) * 8;                                                         \
            GLD16(&A[(size_t)(rowBase + rg + srow) * 512 + (kt) + scolz], SM + (bi)*4096 + rg*64);\
        }                                                                                        \
        _Pragma("unroll") for (int i_ = 0; i_ < 4; ++i_) {                                       \
            int rg = (wid * 4 + i_) * 8;                                                         \
            GLD16(&Bt[(size_t)(colBase + rg + srow) * 512 + (kt) + scolz], SM + 8192 + (bi)*8192 + rg*64);\
        }                                                                                        \
    } while (0)

    f32x4 acc[2][4] = {};
    STG(0, 0);
    for (int ki = 0; ki < 8; ++ki) {
        int bi = ki & 1;
        __syncthreads();
        if (ki < 7) STG(bi ^ 1, (ki + 1) * 64);
#pragma unroll
        for (int kk = 0; kk < 2; ++kk) {
            f16x8 af[2], bf[4];
#pragma unroll
            for (int m = 0; m < 2; ++m)
                af[m] = *(const f16x8*)&SM[bi*4096 + (wm * 32 + m * 16 + l15) * 64 + ((kk * 32 + l4 * 8) ^ kxor)];
#pragma unroll
            for (int n = 0; n < 4; ++n)
                bf[n] = *(const f16x8*)&SM[8192 + bi*8192 + (wn * 64 + n * 16 + l15) * 64 + ((kk * 32 + l4 * 8) ^ kxor)];
#pragma unroll
            for (int m = 0; m < 2; ++m)
#pragma unroll
                for (int n = 0; n < 4; ++n)
                    acc[m][n] = mfma16(af[m], bf[n], acc[m][n]);
        }
    }
#undef STG

    __syncthreads();
    bool isV = (colBase >= 1024);
    if (!isV) {
#pragma unroll
        for (int m = 0; m < 2; ++m)
#pragma unroll
            for (int n = 0; n < 4; ++n)
#pragma unroll
                for (int r = 0; r < 4; ++r)
                    SM[(wm*32 + m*16 + l4*4 + r) * 136 + wn*64 + n*16 + l15] = (f16)acc[m][n][r];
        __syncthreads();
        int rl = tid >> 2, cl0 = (tid & 3) * 32;
        int row = rowBase + rl, bq = row >> 10, nt = row & 1023;
#pragma unroll
        for (int jj = 0; jj < 4; ++jj) {
            f16x8 v = *(const f16x8*)&SM[rl * 136 + cl0 + jj * 8];
            int col = colBase + cl0 + jj * 8;
            int which = col >> 9, hh2 = (col >> 6) & 7, d = col & 63;
            f16* dst = which ? kmat : q;
            *(f16x8*)&dst[((size_t)(bq * 8 + hh2) * 1024 + nt) * 64 + d] = v;
        }
    } else {
#pragma unroll
        for (int m = 0; m < 2; ++m)
#pragma unroll
            for (int n = 0; n < 4; ++n)
#pragma unroll
                for (int r = 0; r < 4; ++r)
                    SM[(wn*64 + n*16 + l15) * 72 + wm*32 + m*16 + l4*4 + r] = (f16)acc[m][n][r];
        __syncthreads();
        int cl = tid >> 1, rl0 = (tid & 1) * 32;
        int col = colBase + cl, hh2 = (col >> 6) & 7, d = col & 63;
        int bq = rowBase >> 10, ntb = (rowBase & 1023) + rl0;
        f16* dstrow = vt + ((size_t)(bq * 8 + hh2) * 64 + d) * 1024 + ntb;
#pragma unroll
        for (int jj = 0; jj < 4; ++jj)
            *(f16x8*)&dstrow[jj * 8] = *(const f16x8*)&SM[cl * 72 + rl0 + jj * 8];
    }
}

// ---- masked flash attention v11: v9 structure + zero-shuffle K=16 PV ----
// 1024 blocks x 512 threads; 32-token chunks; 4 groups x 2 q-slices; dbuf GLD16;
// 1 barrier/iter; P flows softmax -> PV in-lane (no shuffles).
__global__ __launch_bounds__(512, 4) void k_attn(
    const f16* __restrict__ q, const f16* __restrict__ kmat,
    const f16* __restrict__ vt, const int* __restrict__ mlab,
    f16* __restrict__ ao)
{
    __shared__ __align__(16) f16 KV[32768];   // K: (g*2+bi)*2048; V: 16384+(g*2+bi)*2048; merge aliases f32[4][64][64]
    __shared__ float ML[512];                 // m: [g*64+q]; l: [256+g*64+q]

    int bid = blockIdx.x;
    int bh = (bid & 7) + 8 * (bid >> 7);      // all 16 q-blocks of a bh on one XCD
    int qb = (bid >> 3) & 15;
    int b = bh >> 3, hh = bh & 7;
    int tid = threadIdx.x, wid = tid >> 6, lane = tid & 63;
    int g = wid >> 1, qs = wid & 1;
    int l15 = lane & 15, l4 = lane >> 4;
    int qbase = qb * 64;
    size_t bhs = (size_t)bh;

    if (mlab[b * 4 + (qb >> 2)] == 0) return;  // rows filled by k_gemm_out bias path

    unsigned ps = 0; int npres = 0;
#pragma unroll
    for (int s = 0; s < 4; ++s)
        if (mlab[b * 4 + s] != 0) { ps |= (unsigned)s << (4 * npres); ++npres; }
    int niter = npres * 2;                    // 32-token chunks, 4 groups
#define T0C(c) ((int)((ps >> (4 * ((c) >> 3))) & 15) * 256 + ((c) & 7) * 32)

    // Q fragments: rows qs*32 + {0,16} + l15, pre-scaled by 1/8
    f16x8 qf0[2], qf1[2];
#pragma unroll
    for (int kk = 0; kk < 2; ++kk) {
        qf0[kk] = *(const f16x8*)&q[(bhs * 1024 + qbase + qs * 32 + l15) * 64 + kk * 32 + l4 * 8];
        qf1[kk] = *(const f16x8*)&q[(bhs * 1024 + qbase + qs * 32 + 16 + l15) * 64 + kk * 32 + l4 * 8];
#pragma unroll
        for (int j = 0; j < 8; ++j) { qf0[kk][j] = qf0[kk][j] * (f16)0.125; qf1[kk][j] = qf1[kk][j] * (f16)0.125; }
    }

    // staging geometry: group = 2 waves = 128 threads covering 256 slots (2 each)
    int sA = qs * 64 + lane, sB = sA + 128;
    int krA = sA >> 3, kcA = ((sA & 7) ^ (krA & 7)) << 3;
    int krB = sB >> 3, kcB = ((sB & 7) ^ (krB & 7)) << 3;
    int vrA = sA >> 2, vcA = ((sA & 3) ^ ((vrA >> 1) & 3)) << 3;
    int vrB = sB >> 2, vcB = ((sB & 3) ^ ((vrB >> 1) & 3)) << 3;
    const f16* kgA = kmat + (bhs * 1024 + krA) * 64 + kcA;   // + t0*64
    const f16* kgB = kmat + (bhs * 1024 + krB) * 64 + kcB;
    const f16* vgA = vt + (bhs * 64 + vrA) * 1024 + vcA;     // + t0
    const f16* vgB = vt + (bhs * 64 + vrB) * 1024 + vcB;

#define STAGE(bi, t0)                                                \
    do {                                                             \
        f16* kd = KV + (g * 2 + (bi)) * 2048 + qs * 512;             \
        f16* vd = KV + 16384 + (g * 2 + (bi)) * 2048 + qs * 512;     \
        GLD16(kgA + (size_t)(t0) * 64, kd);                          \
        GLD16(kgB + (size_t)(t0) * 64, kd + 1024);                   \
        GLD16(vgA + (t0), vd);                                       \
        GLD16(vgB + (t0), vd + 1024);                                \
    } while (0)

    float mrun0 = -1e30f, mrun1 = -1e30f, lrun0 = 0.f, lrun1 = 0.f;
    f32x4 o0[4] = {}, o1[4] = {};
    int kxor = l15 & 7;
    int vxor = (l15 >> 1) & 3;

    STAGE(0, T0C(g));

    for (int i = 0; i < niter; ++i) {
        int bi = i & 1;
        __syncthreads();                      // buf bi ready; bi^1 free
        if (i + 1 < niter) STAGE(bi ^ 1, T0C(4 * (i + 1) + g));

        const f16* Kt = KV + (g * 2 + bi) * 2048;
        const f16* Vt = KV + 16384 + (g * 2 + bi) * 2048;

        // QK^T both fragments, K reads shared: s[m][n], tok = n*16+l4*4+r, q-col = l15
        f32x4 s00 = {}, s01 = {}, s10 = {}, s11 = {};
        __builtin_amdgcn_s_setprio(1);
#pragma unroll
        for (int kk = 0; kk < 2; ++kk) {
            f16x8 ka0 = *(const f16x8*)&Kt[(0 * 16 + l15) * 64 + (((kk * 4 + l4) ^ kxor) << 3)];
            f16x8 ka1 = *(const f16x8*)&Kt[(1 * 16 + l15) * 64 + (((kk * 4 + l4) ^ kxor) << 3)];
            s00 = mfma16(ka0, qf0[kk], s00);
            s10 = mfma16(ka0, qf1[kk], s10);
            s01 = mfma16(ka1, qf0[kk], s01);
            s11 = mfma16(ka1, qf1[kk], s11);
        }
        __builtin_amdgcn_s_setprio(0);

        // lane-local online softmax; exp values land directly in K=16 B-operand layout
        f16x4 pA0, pB0, pA1, pB1;
        {
            f32x4 mm;
#pragma unroll
            for (int r = 0; r < 4; ++r) mm[r] = fmaxf(s00[r], s01[r]);
            float mx = fmaxf(fmaxf(mm[0], mm[1]), fmaxf(mm[2], mm[3]));
            mx = fmaxf(mx, __shfl_xor(mx, 16));
            mx = fmaxf(mx, __shfl_xor(mx, 32));
            float mnew = fmaxf(mrun0, mx);
            float alpha = __expf(mrun0 - mnew);
            mrun0 = mnew;
            float rs = 0.f;
#pragma unroll
            for (int r = 0; r < 4; ++r) {
                float p0 = __expf(s00[r] - mnew), p1 = __expf(s01[r] - mnew);
                rs += p0 + p1;
                pA0[r] = (f16)p0; pB0[r] = (f16)p1;
            }
            rs += __shfl_xor(rs, 16);
            rs += __shfl_xor(rs, 32);
            lrun0 = lrun0 * alpha + rs;
#pragma unroll
            for (int nd = 0; nd < 4; ++nd) o0[nd] *= alpha;
        }
        {
            f32x4 mm;
#pragma unroll
            for (int r = 0; r < 4; ++r) mm[r] = fmaxf(s10[r], s11[r]);
            float mx = fmaxf(fmaxf(mm[0], mm[1]), fmaxf(mm[2], mm[3]));
            mx = fmaxf(mx, __shfl_xor(mx, 16));
            mx = fmaxf(mx, __shfl_xor(mx, 32));
            float mnew = fmaxf(mrun1, mx);
            float alpha = __expf(mrun1 - mnew);
            mrun1 = mnew;
            float rs = 0.f;
#pragma unroll
            for (int r = 0; r < 4; ++r) {
                float p0 = __expf(s10[r] - mnew), p1 = __expf(s11[r] - mnew);
                rs += p0 + p1;
                pA1[r] = (f16)p0; pB1[r] = (f16)p1;
            }
            rs += __shfl_xor(rs, 16);
            rs += __shfl_xor(rs, 32);
            lrun1 = lrun1 * alpha + rs;
#pragma unroll
            for (int nd = 0; nd < 4; ++nd) o1[nd] *= alpha;
        }

        // PV via K=16 MFMA: va = V^T[d row][tok ck*16 + l4*4 + j] (8B swizzled reads)
        __builtin_amdgcn_s_setprio(1);
#pragma unroll
        for (int nd = 0; nd < 4; ++nd) {
            int row = nd * 16 + l15;
            f16x4 va0 = *(const f16x4*)&Vt[row * 32 + (((l4 >> 1) ^ vxor) << 3) + (l4 & 1) * 4];
            f16x4 va1 = *(const f16x4*)&Vt[row * 32 + (((2 + (l4 >> 1)) ^ vxor) << 3) + (l4 & 1) * 4];
            o0[nd] = mfma16k16(va0, pA0, o0[nd]);
            o1[nd] = mfma16k16(va0, pA1, o1[nd]);
            o0[nd] = mfma16k16(va1, pB0, o0[nd]);
            o1[nd] = mfma16k16(va1, pB1, o1[nd]);
        }
        __builtin_amdgcn_s_setprio(0);
    }
#undef STAGE
#undef T0C

    // ---- publish partials (all groups) ----
    __syncthreads();                          // everyone done with K/V tiles
    float* mg = (float*)KV;                   // [g][q 64][d 64] f32 = 64KB
    int q0 = qs * 32 + l15;
    if (l4 == 0) {
        ML[g * 64 + q0] = mrun0;       ML[256 + g * 64 + q0] = lrun0;
        ML[g * 64 + q0 + 16] = mrun1;  ML[256 + g * 64 + q0 + 16] = lrun1;
    }
    {
        int xr0 = (q0 & 7) << 2, q1 = q0 + 16, xr1 = (q1 & 7) << 2;
#pragma unroll
        for (int nd = 0; nd < 4; ++nd) {
            *(f32x4*)&mg[g * 4096 + q0 * 64 + ((nd * 16 + l4 * 4) ^ xr0)] = o0[nd];
            *(f32x4*)&mg[g * 4096 + q1 * 64 + ((nd * 16 + l4 * 4) ^ xr1)] = o1[nd];
        }
    }
    __syncthreads();

    // ---- distributed 4-way merge; 16B coalesced ao stores ----
    {
        int qq = l15 + l4 * 16;               // 0..63
        float m0 = ML[qq], m1 = ML[64 + qq], m2 = ML[128 + qq], m3 = ML[192 + qq];
        float M = fmaxf(fmaxf(m0, m1), fmaxf(m2, m3));
        float e0 = __expf(m0 - M), e1 = __expf(m1 - M), e2 = __expf(m2 - M), e3 = __expf(m3 - M);
        float L = ML[256 + qq] * e0 + ML[320 + qq] * e1 + ML[384 + qq] * e2 + ML[448 + qq] * e3;
        float inv = 1.f / L;
        int xr = (qq & 7) << 2;
        int Aoff = (wid * 8) ^ xr;
        f32x4 accA = {}, accB = {};
#pragma unroll
        for (int gg = 0; gg < 4; ++gg) {
            float eg = gg == 0 ? e0 : gg == 1 ? e1 : gg == 2 ? e2 : e3;
            f32x4 pa = *(const f32x4*)&mg[gg * 4096 + qq * 64 + Aoff];
            f32x4 pc = *(const f32x4*)&mg[gg * 4096 + qq * 64 + (Aoff ^ 4)];
#pragma unroll
            for (int r = 0; r < 4; ++r) { accA[r] += eg * pa[r]; accB[r] += eg * pc[r]; }
        }
        union { f16 h[8]; f16x8 v; } w;
#pragma unroll
        for (int r = 0; r < 4; ++r) {
            w.h[r] = (f16)(accA[r] * inv);
            w.h[4 + r] = (f16)(accB[r] * inv);
        }
        *(f16x8*)&ao[(size_t)(b * 1024 + qbase + qq) * 512 + hh * 64 + wid * 8] = w.v;
    }
}

// ---- out GEMM: 64x128 tile, LDS dbuf, single barrier/K-step, swizzled ----
__global__ __launch_bounds__(256, 3) void k_gemm_out(
    const f16* __restrict__ A, const f16* __restrict__ Bt, const int* __restrict__ mlab,
    const float* __restrict__ bias, float* __restrict__ out)
{
    __shared__ f16 As[2][64 * 64];
    __shared__ f16 Bs[2][128 * 64];
    int tid = threadIdx.x, wid = tid >> 6, lane = tid & 63;
    int wm = wid >> 1, wn = wid & 1;
    int l15 = lane & 15, l4 = lane >> 4;
    int rowBase = blockIdx.y * 64;
    int colBase = blockIdx.x * 128;
    if (mlab[(rowBase >> 10) * 4 + ((rowBase & 1023) >> 8)] == 0) {
        for (int i = tid; i < 64 * 128; i += 256)
            out[(size_t)(rowBase + (i >> 7)) * 512 + colBase + (i & 127)] = bias[colBase + (i & 127)];
        return;
    }

    int srow = lane >> 3;
    int scolz = ((lane & 7) ^ srow) << 3;
    int kxor = (l15 & 7) << 3;

#define STG(bi, kt)                                                                         \
    do {                                                                                    \
        _Pragma("unroll") for (int i_ = 0; i_ < 2; ++i_) {                                  \
            int rg = (wid * 2 + i_) * 8;                                                    \
            GLD16(&A[(size_t)(rowBase + rg + srow) * 512 + (kt) + scolz], &As[bi][rg * 64]);\
        }                                                                                   \
        _Pragma("unroll") for (int i_ = 0; i_ < 4; ++i_) {                                  \
            int rg = (wid * 4 + i_) * 8;                                                    \
            GLD16(&Bt[(size_t)(colBase + rg + srow) * 512 + (kt) + scolz], &Bs[bi][rg * 64]);\
        }                                                                                   \
    } while (0)

    f32x4 acc[2][4] = {};
    STG(0, 0);
    for (int ki = 0; ki < 8; ++ki) {
        int bi = ki & 1;
        __syncthreads();
        if (ki < 7) STG(bi ^ 1, (ki + 1) * 64);
#pragma unroll
        for (int kk = 0; kk < 2; ++kk) {
            f16x8 af[2], bf[4];
#pragma unroll
            for (int m = 0; m < 2; ++m)
                af[m] = *(const f16x8*)&As[bi][(wm * 32 + m * 16 + l15) * 64 + ((kk * 32 + l4 * 8) ^ kxor)];
#pragma unroll
            for (int n = 0; n < 4; ++n)
                bf[n] = *(const f16x8*)&Bs[bi][(wn * 64 + n * 16 + l15) * 64 + ((kk * 32 + l4 * 8) ^ kxor)];
#pragma unroll
            for (int m = 0; m < 2; ++m)
#pragma unroll
                for (int n = 0; n < 4; ++n)
                    acc[m][n] = mfma16(af[m], bf[n], acc[m][n]);
        }
    }
#undef STG
#pragma unroll
    for (int m = 0; m < 2; ++m)
#pragma unroll
        for (int n = 0; n < 4; ++n)
#pragma unroll
            for (int r = 0; r < 4; ++r) {
                int row = rowBase + wm * 32 + m * 16 + l4 * 4 + r;
                int col = colBase + wn * 64 + n * 16 + l15;
                out[(size_t)row * 512 + col] = acc[m][n][r] + bias[col];
            }
}

extern "C" void kernel_launch(void* const* d_in, const int* in_sizes, int n_in,
                              void* d_out, int out_size, void* d_ws, size_t ws_size,
                              hipStream_t stream) {
    const float* x     = (const float*)d_in[0];
    const int*   mlab  = (const int*)d_in[1];
    const float* gamma = (const float*)d_in[2];
    const float* beta  = (const float*)d_in[3];
    const float* wqkv  = (const float*)d_in[4];
    const float* wout  = (const float*)d_in[5];
    const float* bout  = (const float*)d_in[6];
    float* out = (float*)d_out;

    f16* h     = (f16*)d_ws;                 // 8192*512
    f16* wqkvT = h + 8192 * 512;             // 1536*512
    f16* woutT = wqkvT + 1536 * 512;         // 512*512
    f16* q     = woutT + 512 * 512;          // [B*H][1024][64]
    f16* kmat  = q + 4 * 1024 * 1024;
    f16* vt    = kmat + 4 * 1024 * 1024;     // [B*H][64][1024]
    f16* ao    = h;                          // h dead after QKV GEMM -> reuse

    k_prep<<<2304, 256, 0, stream>>>(x, gamma, beta, mlab, wqkv, wout, h, wqkvT, woutT);
    k_gemm_qkv<<<dim3(12, 128), 256, 0, stream>>>(h, wqkvT, mlab, q, kmat, vt);
    k_attn<<<1024, 512, 0, stream>>>(q, kmat, vt, mlab, ao);
    k_gemm_out<<<dim3(4, 128), 256, 0, stream>>>(ao, woutT, mlab, bout, out);
}

// Round 12
// 60.618 us; speedup vs baseline: 1.1799x; 1.0065x over previous
//
#include <hip/hip_runtime.h>

typedef _Float16 f16;
typedef _Float16 f16x4 __attribute__((ext_vector_type(4)));
typedef _Float16 f16x8 __attribute__((ext_vector_type(8)));
typedef float f32x4 __attribute__((ext_vector_type(4)));

typedef __attribute__((address_space(1))) void gvoid;
typedef __attribute__((address_space(3))) void lvoid;
#define GLD16(gp, lp) __builtin_amdgcn_global_load_lds((gvoid*)(gp), (lvoid*)(lp), 16, 0, 0)

__device__ __forceinline__ f32x4 mfma16(f16x8 a, f16x8 b, f32x4 c) {
    return __builtin_amdgcn_mfma_f32_16x16x32_f16(a, b, c, 0, 0, 0);
}
__device__ __forceinline__ f32x4 mfma16k16(f16x4 a, f16x4 b, f32x4 c) {
    return __builtin_amdgcn_mfma_f32_16x16x16f16(a, b, c, 0, 0, 0);
}

// ---- prep: LN (blocks 0..2047) + wqkv transpose (2048..2239) + wout transpose (2240..2303)
__global__ __launch_bounds__(256) void k_prep(
    const float* __restrict__ x, const float* __restrict__ gamma,
    const float* __restrict__ beta, const int* __restrict__ mlab,
    const float* __restrict__ wqkv, const float* __restrict__ wout,
    f16* __restrict__ h, f16* __restrict__ wqkvT, f16* __restrict__ woutT)
{
    __shared__ float t[64][65];
    int bid = blockIdx.x, tid = threadIdx.x;
    if (bid < 2048) {                       // ---- LayerNorm, 1 wave/row ----
        int row = bid * 4 + (tid >> 6);
        int b = row >> 10, seg = (row >> 8) & 3;
        if (mlab[b * 4 + seg] == 0) return;
        int lane = tid & 63;
        const float* xr = x + (size_t)row * 512;
        float4 a = ((const float4*)xr)[lane * 2];
        float4 bv = ((const float4*)xr)[lane * 2 + 1];
        float v[8] = {a.x, a.y, a.z, a.w, bv.x, bv.y, bv.z, bv.w};
        float s = 0.f, s2 = 0.f;
#pragma unroll
        for (int j = 0; j < 8; ++j) { s += v[j]; s2 += v[j] * v[j]; }
#pragma unroll
        for (int off = 1; off < 64; off <<= 1) {
            s  += __shfl_xor(s, off);
            s2 += __shfl_xor(s2, off);
        }
        float mu  = s * (1.f / 512.f);
        float var = s2 * (1.f / 512.f) - mu * mu;
        float rstd = rsqrtf(var + 1e-5f);
        float4 g0 = ((const float4*)gamma)[lane * 2];
        float4 g1 = ((const float4*)gamma)[lane * 2 + 1];
        float4 b0 = ((const float4*)beta)[lane * 2];
        float4 b1 = ((const float4*)beta)[lane * 2 + 1];
        float g[8]  = {g0.x, g0.y, g0.z, g0.w, g1.x, g1.y, g1.z, g1.w};
        float bb[8] = {b0.x, b0.y, b0.z, b0.w, b1.x, b1.y, b1.z, b1.w};
        f16x8 o;
#pragma unroll
        for (int j = 0; j < 8; ++j) o[j] = (f16)((v[j] - mu) * rstd * g[j] + bb[j]);
        *(f16x8*)&h[(size_t)row * 512 + lane * 8] = o;
        return;
    }
    const float* in; f16* out; int C, c0, r0;
    if (bid < 2240) { int idx = bid - 2048; in = wqkv; out = wqkvT; C = 1536; c0 = (idx % 24) * 64; r0 = (idx / 24) * 64; }
    else            { int idx = bid - 2240; in = wout; out = woutT; C = 512;  c0 = (idx % 8)  * 64; r0 = (idx / 8)  * 64; }
#pragma unroll
    for (int i = 0; i < 16; ++i) {
        int r = i * 4 + (tid >> 6), c = tid & 63;
        t[r][c] = in[(size_t)(r0 + r) * C + c0 + c];
    }
    __syncthreads();
#pragma unroll
    for (int i = 0; i < 16; ++i) {
        int cr = i * 4 + (tid >> 6), cc = tid & 63;
        out[(size_t)(c0 + cr) * 512 + r0 + cc] = (f16)t[cc][cr];
    }
}

// ---- QKV GEMM: 64x128 tile, BK=64, LDS dbuf, swizzled; LDS-repacked 16B epilogue ----
__global__ __launch_bounds__(256, 3) void k_gemm_qkv(
    const f16* __restrict__ A, const f16* __restrict__ Bt, const int* __restrict__ mlab,
    f16* __restrict__ q, f16* __restrict__ kmat, f16* __restrict__ vt)
{
    __shared__ __align__(16) f16 SM[24576];
    int tid = threadIdx.x, wid = tid >> 6, lane = tid & 63;
    int wm = wid >> 1, wn = wid & 1;
    int l15 = lane & 15, l4 = lane >> 4;
    int rowBase = blockIdx.y * 64;
    int colBase = blockIdx.x * 128;
    if (mlab[(rowBase >> 10) * 4 + ((rowBase & 1023) >> 8)] == 0) return;

    int srow = lane >> 3;
    int scolz = ((lane & 7) ^ srow) << 3;
    int kxor = (l15 & 7) << 3;

#define STG(bi, kt)                                                                              \
    do {                                                                                         \
        _Pragma("unroll") for (int i_ = 0; i_ < 2; ++i_) {                                       \
            int rg = (wid * 2 + i_) * 8;                                                         \
            GLD16(&A[(size_t)(rowBase + rg + srow) * 512 + (kt) + scolz], SM + (bi)*4096 + rg*64);\
        }                                                                                        \
        _Pragma("unroll") for (int i_ = 0; i_ < 4; ++i_) {                                       \
            int rg = (wid * 4 + i_) * 8;                                                         \
            GLD16(&Bt[(size_t)(colBase + rg + srow) * 512 + (kt) + scolz], SM + 8192 + (bi)*8192 + rg*64);\
        }                                                                                        \
    } while (0)

    f32x4 acc[2][4] = {};
    STG(0, 0);
    for (int ki = 0; ki < 8; ++ki) {
        int bi = ki & 1;
        __syncthreads();
        if (ki < 7) STG(bi ^ 1, (ki + 1) * 64);
#pragma unroll
        for (int kk = 0; kk < 2; ++kk) {
            f16x8 af[2], bf[4];
#pragma unroll
            for (int m = 0; m < 2; ++m)
                af[m] = *(const f16x8*)&SM[bi*4096 + (wm * 32 + m * 16 + l15) * 64 + ((kk * 32 + l4 * 8) ^ kxor)];
#pragma unroll
            for (int n = 0; n < 4; ++n)
                bf[n] = *(const f16x8*)&SM[8192 + bi*8192 + (wn * 64 + n * 16 + l15) * 64 + ((kk * 32 + l4 * 8) ^ kxor)];
#pragma unroll
            for (int m = 0; m < 2; ++m)
#pragma unroll
                for (int n = 0; n < 4; ++n)
                    acc[m][n] = mfma16(af[m], bf[n], acc[m][n]);
        }
    }
#undef STG

    __syncthreads();
    bool isV = (colBase >= 1024);
    if (!isV) {
#pragma unroll
        for (int m = 0; m < 2; ++m)
#pragma unroll
            for (int n = 0; n < 4; ++n)
#pragma unroll
                for (int r = 0; r < 4; ++r)
                    SM[(wm*32 + m*16 + l4*4 + r) * 136 + wn*64 + n*16 + l15] = (f16)acc[m][n][r];
        __syncthreads();
        int rl = tid >> 2, cl0 = (tid & 3) * 32;
        int row = rowBase + rl, bq = row >> 10, nt = row & 1023;
#pragma unroll
        for (int jj = 0; jj < 4; ++jj) {
            f16x8 v = *(const f16x8*)&SM[rl * 136 + cl0 + jj * 8];
            int col = colBase + cl0 + jj * 8;
            int which = col >> 9, hh2 = (col >> 6) & 7, d = col & 63;
            f16* dst = which ? kmat : q;
            *(f16x8*)&dst[((size_t)(bq * 8 + hh2) * 1024 + nt) * 64 + d] = v;
        }
    } else {
#pragma unroll
        for (int m = 0; m < 2; ++m)
#pragma unroll
            for (int n = 0; n < 4; ++n)
#pragma unroll
                for (int r = 0; r < 4; ++r)
                    SM[(wn*64 + n*16 + l15) * 72 + wm*32 + m*16 + l4*4 + r] = (f16)acc[m][n][r];
        __syncthreads();
        int cl = tid >> 1, rl0 = (tid & 1) * 32;
        int col = colBase + cl, hh2 = (col >> 6) & 7, d = col & 63;
        int bq = rowBase >> 10, ntb = (rowBase & 1023) + rl0;
        f16* dstrow = vt + ((size_t)(bq * 8 + hh2) * 64 + d) * 1024 + ntb;
#pragma unroll
        for (int jj = 0; jj < 4; ++jj)
            *(f16x8*)&dstrow[jj * 8] = *(const f16x8*)&SM[cl * 72 + rl0 + jj * 8];
    }
}

// ---- masked flash attention v12: v11 minus setprio (lockstep waves -> T5 null) ----
__global__ __launch_bounds__(512, 4) void k_attn(
    const f16* __restrict__ q, const f16* __restrict__ kmat,
    const f16* __restrict__ vt, const int* __restrict__ mlab,
    f16* __restrict__ ao)
{
    __shared__ __align__(16) f16 KV[32768];
    __shared__ float ML[512];

    int bid = blockIdx.x;
    int bh = (bid & 7) + 8 * (bid >> 7);
    int qb = (bid >> 3) & 15;
    int b = bh >> 3, hh = bh & 7;
    int tid = threadIdx.x, wid = tid >> 6, lane = tid & 63;
    int g = wid >> 1, qs = wid & 1;
    int l15 = lane & 15, l4 = lane >> 4;
    int qbase = qb * 64;
    size_t bhs = (size_t)bh;

    if (mlab[b * 4 + (qb >> 2)] == 0) return;

    unsigned ps = 0; int npres = 0;
#pragma unroll
    for (int s = 0; s < 4; ++s)
        if (mlab[b * 4 + s] != 0) { ps |= (unsigned)s << (4 * npres); ++npres; }
    int niter = npres * 2;
#define T0C(c) ((int)((ps >> (4 * ((c) >> 3))) & 15) * 256 + ((c) & 7) * 32)

    f16x8 qf0[2], qf1[2];
#pragma unroll
    for (int kk = 0; kk < 2; ++kk) {
        qf0[kk] = *(const f16x8*)&q[(bhs * 1024 + qbase + qs * 32 + l15) * 64 + kk * 32 + l4 * 8];
        qf1[kk] = *(const f16x8*)&q[(bhs * 1024 + qbase + qs * 32 + 16 + l15) * 64 + kk * 32 + l4 * 8];
#pragma unroll
        for (int j = 0; j < 8; ++j) { qf0[kk][j] = qf0[kk][j] * (f16)0.125; qf1[kk][j] = qf1[kk][j] * (f16)0.125; }
    }

    int sA = qs * 64 + lane, sB = sA + 128;
    int krA = sA >> 3, kcA = ((sA & 7) ^ (krA & 7)) << 3;
    int krB = sB >> 3, kcB = ((sB & 7) ^ (krB & 7)) << 3;
    int vrA = sA >> 2, vcA = ((sA & 3) ^ ((vrA >> 1) & 3)) << 3;
    int vrB = sB >> 2, vcB = ((sB & 3) ^ ((vrB >> 1) & 3)) << 3;
    const f16* kgA = kmat + (bhs * 1024 + krA) * 64 + kcA;
    const f16* kgB = kmat + (bhs * 1024 + krB) * 64 + kcB;
    const f16* vgA = vt + (bhs * 64 + vrA) * 1024 + vcA;
    const f16* vgB = vt + (bhs * 64 + vrB) * 1024 + vcB;

#define STAGE(bi, t0)                                                \
    do {                                                             \
        f16* kd = KV + (g * 2 + (bi)) * 2048 + qs * 512;             \
        f16* vd = KV + 16384 + (g * 2 + (bi)) * 2048 + qs * 512;     \
        GLD16(kgA + (size_t)(t0) * 64, kd);                          \
        GLD16(kgB + (size_t)(t0) * 64, kd + 1024);                   \
        GLD16(vgA + (t0), vd);                                       \
        GLD16(vgB + (t0), vd + 1024);                                \
    } while (0)

    float mrun0 = -1e30f, mrun1 = -1e30f, lrun0 = 0.f, lrun1 = 0.f;
    f32x4 o0[4] = {}, o1[4] = {};
    int kxor = l15 & 7;
    int vxor = (l15 >> 1) & 3;

    STAGE(0, T0C(g));

    for (int i = 0; i < niter; ++i) {
        int bi = i & 1;
        __syncthreads();
        if (i + 1 < niter) STAGE(bi ^ 1, T0C(4 * (i + 1) + g));

        const f16* Kt = KV + (g * 2 + bi) * 2048;
        const f16* Vt = KV + 16384 + (g * 2 + bi) * 2048;

        f32x4 s00 = {}, s01 = {}, s10 = {}, s11 = {};
#pragma unroll
        for (int kk = 0; kk < 2; ++kk) {
            f16x8 ka0 = *(const f16x8*)&Kt[(0 * 16 + l15) * 64 + (((kk * 4 + l4) ^ kxor) << 3)];
            f16x8 ka1 = *(const f16x8*)&Kt[(1 * 16 + l15) * 64 + (((kk * 4 + l4) ^ kxor) << 3)];
            s00 = mfma16(ka0, qf0[kk], s00);
            s10 = mfma16(ka0, qf1[kk], s10);
            s01 = mfma16(ka1, qf0[kk], s01);
            s11 = mfma16(ka1, qf1[kk], s11);
        }

        f16x4 pA0, pB0, pA1, pB1;
        {
            f32x4 mm;
#pragma unroll
            for (int r = 0; r < 4; ++r) mm[r] = fmaxf(s00[r], s01[r]);
            float mx = fmaxf(fmaxf(mm[0], mm[1]), fmaxf(mm[2], mm[3]));
            mx = fmaxf(mx, __shfl_xor(mx, 16));
            mx = fmaxf(mx, __shfl_xor(mx, 32));
            float mnew = fmaxf(mrun0, mx);
            float alpha = __expf(mrun0 - mnew);
            mrun0 = mnew;
            float rs = 0.f;
#pragma unroll
            for (int r = 0; r < 4; ++r) {
                float p0 = __expf(s00[r] - mnew), p1 = __expf(s01[r] - mnew);
                rs += p0 + p1;
                pA0[r] = (f16)p0; pB0[r] = (f16)p1;
            }
            rs += __shfl_xor(rs, 16);
            rs += __shfl_xor(rs, 32);
            lrun0 = lrun0 * alpha + rs;
#pragma unroll
            for (int nd = 0; nd < 4; ++nd) o0[nd] *= alpha;
        }
        {
            f32x4 mm;
#pragma unroll
            for (int r = 0; r < 4; ++r) mm[r] = fmaxf(s10[r], s11[r]);
            float mx = fmaxf(fmaxf(mm[0], mm[1]), fmaxf(mm[2], mm[3]));
            mx = fmaxf(mx, __shfl_xor(mx, 16));
            mx = fmaxf(mx, __shfl_xor(mx, 32));
            float mnew = fmaxf(mrun1, mx);
            float alpha = __expf(mrun1 - mnew);
            mrun1 = mnew;
            float rs = 0.f;
#pragma unroll
            for (int r = 0; r < 4; ++r) {
                float p0 = __expf(s10[r] - mnew), p1 = __expf(s11[r] - mnew);
                rs += p0 + p1;
                pA1[r] = (f16)p0; pB1[r] = (f16)p1;
            }
            rs += __shfl_xor(rs, 16);
            rs += __shfl_xor(rs, 32);
            lrun1 = lrun1 * alpha + rs;
#pragma unroll
            for (int nd = 0; nd < 4; ++nd) o1[nd] *= alpha;
        }

#pragma unroll
        for (int nd = 0; nd < 4; ++nd) {
            int row = nd * 16 + l15;
            f16x4 va0 = *(const f16x4*)&Vt[row * 32 + (((l4 >> 1) ^ vxor) << 3) + (l4 & 1) * 4];
            f16x4 va1 = *(const f16x4*)&Vt[row * 32 + (((2 + (l4 >> 1)) ^ vxor) << 3) + (l4 & 1) * 4];
            o0[nd] = mfma16k16(va0, pA0, o0[nd]);
            o1[nd] = mfma16k16(va0, pA1, o1[nd]);
            o0[nd] = mfma16k16(va1, pB0, o0[nd]);
            o1[nd] = mfma16k16(va1, pB1, o1[nd]);
        }
    }
#undef STAGE
#undef T0C

    __syncthreads();
    float* mg = (float*)KV;
    int q0 = qs * 32 + l15;
    if (l4 == 0) {
        ML[g * 64 + q0] = mrun0;       ML[256 + g * 64 + q0] = lrun0;
        ML[g * 64 + q0 + 16] = mrun1;  ML[256 + g * 64 + q0 + 16] = lrun1;
    }
    {
        int xr0 = (q0 & 7) << 2, q1 = q0 + 16, xr1 = (q1 & 7) << 2;
#pragma unroll
        for (int nd = 0; nd < 4; ++nd) {
            *(f32x4*)&mg[g * 4096 + q0 * 64 + ((nd * 16 + l4 * 4) ^ xr0)] = o0[nd];
            *(f32x4*)&mg[g * 4096 + q1 * 64 + ((nd * 16 + l4 * 4) ^ xr1)] = o1[nd];
        }
    }
    __syncthreads();

    {
        int qq = l15 + l4 * 16;
        float m0 = ML[qq], m1 = ML[64 + qq], m2 = ML[128 + qq], m3 = ML[192 + qq];
        float M = fmaxf(fmaxf(m0, m1), fmaxf(m2, m3));
        float e0 = __expf(m0 - M), e1 = __expf(m1 - M), e2 = __expf(m2 - M), e3 = __expf(m3 - M);
        float L = ML[256 + qq] * e0 + ML[320 + qq] * e1 + ML[384 + qq] * e2 + ML[448 + qq] * e3;
        float inv = 1.f / L;
        int xr = (qq & 7) << 2;
        int Aoff = (wid * 8) ^ xr;
        f32x4 accA = {}, accB = {};
#pragma unroll
        for (int gg = 0; gg < 4; ++gg) {
            float eg = gg == 0 ? e0 : gg == 1 ? e1 : gg == 2 ? e2 : e3;
            f32x4 pa = *(const f32x4*)&mg[gg * 4096 + qq * 64 + Aoff];
            f32x4 pc = *(const f32x4*)&mg[gg * 4096 + qq * 64 + (Aoff ^ 4)];
#pragma unroll
            for (int r = 0; r < 4; ++r) { accA[r] += eg * pa[r]; accB[r] += eg * pc[r]; }
        }
        union { f16 h[8]; f16x8 v; } w;
#pragma unroll
        for (int r = 0; r < 4; ++r) {
            w.h[r] = (f16)(accA[r] * inv);
            w.h[4 + r] = (f16)(accB[r] * inv);
        }
        *(f16x8*)&ao[(size_t)(b * 1024 + qbase + qq) * 512 + hh * 64 + wid * 8] = w.v;
    }
}

// ---- out GEMM: 64x64 tile (2 active blocks/CU -> barrier overlap), LDS dbuf, swizzled ----
__global__ __launch_bounds__(256, 4) void k_gemm_out(
    const f16* __restrict__ A, const f16* __restrict__ Bt, const int* __restrict__ mlab,
    const float* __restrict__ bias, float* __restrict__ out)
{
    __shared__ f16 As[2][64 * 64];
    __shared__ f16 Bs[2][64 * 64];
    int tid = threadIdx.x, wid = tid >> 6, lane = tid & 63;
    int wm = wid >> 1, wn = wid & 1;
    int l15 = lane & 15, l4 = lane >> 4;
    int rowBase = blockIdx.y * 64;
    int colBase = blockIdx.x * 64;
    if (mlab[(rowBase >> 10) * 4 + ((rowBase & 1023) >> 8)] == 0) {
        for (int i = tid; i < 64 * 64; i += 256)
            out[(size_t)(rowBase + (i >> 6)) * 512 + colBase + (i & 63)] = bias[colBase + (i & 63)];
        return;
    }

    int srow = lane >> 3;
    int scolz = ((lane & 7) ^ srow) << 3;
    int kxor = (l15 & 7) << 3;

#define STG(bi, kt)                                                                         \
    do {                                                                                    \
        _Pragma("unroll") for (int i_ = 0; i_ < 2; ++i_) {                                  \
            int rg = (wid * 2 + i_) * 8;                                                    \
            GLD16(&A[(size_t)(rowBase + rg + srow) * 512 + (kt) + scolz], &As[bi][rg * 64]);\
            GLD16(&Bt[(size_t)(colBase + rg + srow) * 512 + (kt) + scolz], &Bs[bi][rg * 64]);\
        }                                                                                   \
    } while (0)

    f32x4 acc[2][2] = {};
    STG(0, 0);
    for (int ki = 0; ki < 8; ++ki) {
        int bi = ki & 1;
        __syncthreads();
        if (ki < 7) STG(bi ^ 1, (ki + 1) * 64);
#pragma unroll
        for (int kk = 0; kk < 2; ++kk) {
            f16x8 af[2], bf[2];
#pragma unroll
            for (int m = 0; m < 2; ++m)
                af[m] = *(const f16x8*)&As[bi][(wm * 32 + m * 16 + l15) * 64 + ((kk * 32 + l4 * 8) ^ kxor)];
#pragma unroll
            for (int n = 0; n < 2; ++n)
                bf[n] = *(const f16x8*)&Bs[bi][(wn * 32 + n * 16 + l15) * 64 + ((kk * 32 + l4 * 8) ^ kxor)];
#pragma unroll
            for (int m = 0; m < 2; ++m)
#pragma unroll
                for (int n = 0; n < 2; ++n)
                    acc[m][n] = mfma16(af[m], bf[n], acc[m][n]);
        }
    }
#undef STG
#pragma unroll
    for (int m = 0; m < 2; ++m)
#pragma unroll
        for (int n = 0; n < 2; ++n)
#pragma unroll
            for (int r = 0; r < 4; ++r) {
                int row = rowBase + wm * 32 + m * 16 + l4 * 4 + r;
                int col = colBase + wn * 32 + n * 16 + l15;
                out[(size_t)row * 512 + col] = acc[m][n][r] + bias[col];
            }
}

extern "C" void kernel_launch(void* const* d_in, const int* in_sizes, int n_in,
                              void* d_out, int out_size, void* d_ws, size_t ws_size,
                              hipStream_t stream) {
    const float* x     = (const float*)d_in[0];
    const int*   mlab  = (const int*)d_in[1];
    const float* gamma = (const float*)d_in[2];
    const float* beta  = (const float*)d_in[3];
    const float* wqkv  = (const float*)d_in[4];
    const float* wout  = (const float*)d_in[5];
    const float* bout  = (const float*)d_in[6];
    float* out = (float*)d_out;

    f16* h     = (f16*)d_ws;                 // 8192*512
    f16* wqkvT = h + 8192 * 512;             // 1536*512
    f16* woutT = wqkvT + 1536 * 512;         // 512*512
    f16* q     = woutT + 512 * 512;          // [B*H][1024][64]
    f16* kmat  = q + 4 * 1024 * 1024;
    f16* vt    = kmat + 4 * 1024 * 1024;     // [B*H][64][1024]
    f16* ao    = h;                          // h dead after QKV GEMM -> reuse

    k_prep<<<2304, 256, 0, stream>>>(x, gamma, beta, mlab, wqkv, wout, h, wqkvT, woutT);
    k_gemm_qkv<<<dim3(12, 128), 256, 0, stream>>>(h, wqkvT, mlab, q, kmat, vt);
    k_attn<<<1024, 512, 0, stream>>>(q, kmat, vt, mlab, ao);
    k_gemm_out<<<dim3(8, 128), 256, 0, stream>>>(ao, woutT, mlab, bout, out);
}